// Round 1
// baseline (660.821 us; speedup 1.0000x reference)
//
#include <hip/hip_runtime.h>

#define BATCH 256
#define SEQ   512
#define HDIM  768
#define WDIM  25
#define NLAB  42
#define CIN   2354        // 768*2 + 25*2 + 768
#define E1W_OFF 1536
#define E2W_OFF 1561
#define CTX_OFF 1586
#define MAXW  10

// ---------------------------------------------------------------------------
// K0: build combined[B, CIN] = [e1_repr | e2_repr | e1_w | e2_w | ctx]
// grid (6, 256): blockIdx.y = batch, blockIdx.x = 128-wide H chunk.
// ---------------------------------------------------------------------------
__global__ __launch_bounds__(128) void build_combined(
    const float* __restrict__ seq,
    const int* __restrict__ e1p, const int* __restrict__ e2p,
    const int* __restrict__ e1l, const int* __restrict__ e2l,
    const float* __restrict__ wemb,
    float* __restrict__ comb) {
  const int b = blockIdx.y;
  const int c = blockIdx.x;            // 0..5
  const int t = threadIdx.x;           // 0..127
  const int h = c * 128 + t;

  const int e1 = e1p[b];
  const int e2 = e2p[b];
  const float* row = seq + (size_t)b * SEQ * HDIM;
  float* crow = comb + (size_t)b * CIN;

  // entity token reps (coalesced 128-float chunk per block)
  crow[h]        = row[e1 * HDIM + h];
  crow[HDIM + h] = row[e2 * HDIM + h];

  // masked mean over tokens strictly between e1 and e2
  const int s0 = e1 + 1;
  const int cnt = e2 - s0;             // may be <= 0
  const int n = cnt > 0 ? cnt : 0;
  float acc = 0.f;
  const float* p = row + s0 * HDIM + h;
  int i = 0;
  for (; i + 4 <= n; i += 4) {
    float a0 = p[0 * HDIM], a1 = p[1 * HDIM], a2 = p[2 * HDIM], a3 = p[3 * HDIM];
    acc += (a0 + a1) + (a2 + a3);
    p += 4 * HDIM;
  }
  for (; i < n; ++i) { acc += *p; p += HDIM; }
  crow[CTX_OFF + h] = (n > 0) ? acc / (float)n : 0.f;

  // width embeddings: block c==0 only (25 floats each)
  if (c == 0) {
    if (t < WDIM) {
      int w = e1l[b]; w = w < 0 ? 0 : (w > MAXW ? MAXW : w);
      crow[E1W_OFF + t] = wemb[w * WDIM + t];
    } else if (t >= 64 && t < 64 + WDIM) {
      int tt = t - 64;
      int w = e2l[b]; w = w < 0 ? 0 : (w > MAXW ? MAXW : w);
      crow[E2W_OFF + tt] = wemb[w * WDIM + tt];
    }
  }
}

// ---------------------------------------------------------------------------
// K1: split-K GEMM  hpart[ks][m][n] = combined[m, kchunk] @ W1[kchunk, n]
// M=256, N=768, K=2354. BM=32, BN=64, BK=16, SPLITK=3 -> 12*8*3 = 288 blocks.
// 256 threads, 2m x 4n register tile per thread. Plain stores (no atomics).
// ---------------------------------------------------------------------------
#define BM 32
#define BN 64
#define BK 16
#define SPLITK 3

__global__ __launch_bounds__(256) void gemm1(
    const float* __restrict__ comb,
    const float* __restrict__ W1,
    float* __restrict__ hpart) {
  const int nt = blockIdx.x;           // 0..11
  const int mt = blockIdx.y;           // 0..7
  const int ks = blockIdx.z;           // 0..2
  const int tid = threadIdx.x;

  const int KCH = (CIN + SPLITK - 1) / SPLITK;   // 785
  const int k0 = ks * KCH;
  const int kend = min(k0 + KCH, CIN);
  const int m0 = mt * BM;
  const int n0 = nt * BN;

  __shared__ float As[BK][BM + 2];     // transposed: As[k][m]; +2 pad -> 2-way max
  __shared__ float Bs[BK][BN];

  const int tx = tid & 15;             // n group (4 cols each)
  const int ty = tid >> 4;             // m group (2 rows each), 0..15

  const int a_c = tid & 15;            // k within tile
  const int a_r = tid >> 4;            // m row, +16 for second elem
  const int b_n = tid & 63;
  const int b_k = tid >> 6;            // 0..3, step 4

  float acc[2][4] = {{0.f,0.f,0.f,0.f},{0.f,0.f,0.f,0.f}};

  for (int kk = k0; kk < kend; kk += BK) {
#pragma unroll
    for (int i = 0; i < 2; ++i) {
      int m = a_r + i * 16;
      int k = kk + a_c;
      As[a_c][m] = (k < kend) ? comb[(m0 + m) * CIN + k] : 0.f;
    }
#pragma unroll
    for (int i = 0; i < 4; ++i) {
      int kr = b_k + i * 4;
      int kg = kk + kr;
      Bs[kr][b_n] = (kg < kend) ? W1[kg * HDIM + n0 + b_n] : 0.f;
    }
    __syncthreads();
#pragma unroll
    for (int k = 0; k < BK; ++k) {
      float a0 = As[k][ty * 2 + 0];
      float a1 = As[k][ty * 2 + 1];
      const float4* bp = (const float4*)&Bs[k][0];
      float4 bv = bp[tx];
      acc[0][0] += a0 * bv.x; acc[0][1] += a0 * bv.y;
      acc[0][2] += a0 * bv.z; acc[0][3] += a0 * bv.w;
      acc[1][0] += a1 * bv.x; acc[1][1] += a1 * bv.y;
      acc[1][2] += a1 * bv.z; acc[1][3] += a1 * bv.w;
    }
    __syncthreads();
  }

  float* outp = hpart + (size_t)ks * BATCH * HDIM;
#pragma unroll
  for (int i = 0; i < 2; ++i) {
    int m = m0 + ty * 2 + i;
    float4 v = make_float4(acc[i][0], acc[i][1], acc[i][2], acc[i][3]);
    *(float4*)&outp[m * HDIM + n0 + tx * 4] = v;
  }
}

// ---------------------------------------------------------------------------
// K2: sum split-K partials, +b1, ReLU, then [768] x W2[768,42] + b2 -> out.
// One wave per batch row; 256 blocks.
// ---------------------------------------------------------------------------
__global__ __launch_bounds__(64) void gemm2(
    const float* __restrict__ hpart,
    const float* __restrict__ b1,
    const float* __restrict__ W2,
    const float* __restrict__ b2,
    float* __restrict__ out) {
  const int m = blockIdx.x;
  const int lane = threadIdx.x;
  __shared__ float hs[HDIM];

  const float* p0 = hpart + m * HDIM;
  const float* p1 = p0 + BATCH * HDIM;
  const float* p2 = p1 + BATCH * HDIM;
  for (int i = lane; i < HDIM; i += 64) {
    float v = p0[i] + p1[i] + p2[i] + b1[i];
    hs[i] = v > 0.f ? v : 0.f;
  }
  __syncthreads();

  if (lane < NLAB) {
    float a0 = 0.f, a1 = 0.f, a2 = 0.f, a3 = 0.f;
    for (int n = 0; n < HDIM; n += 4) {
      a0 += hs[n + 0] * W2[(n + 0) * NLAB + lane];
      a1 += hs[n + 1] * W2[(n + 1) * NLAB + lane];
      a2 += hs[n + 2] * W2[(n + 2) * NLAB + lane];
      a3 += hs[n + 3] * W2[(n + 3) * NLAB + lane];
    }
    out[m * NLAB + lane] = b2[lane] + (a0 + a1) + (a2 + a3);
  }
}

// ---------------------------------------------------------------------------
extern "C" void kernel_launch(void* const* d_in, const int* in_sizes, int n_in,
                              void* d_out, int out_size, void* d_ws, size_t ws_size,
                              hipStream_t stream) {
  const float* seq  = (const float*)d_in[0];
  const int*   e1p  = (const int*)d_in[1];
  const int*   e2p  = (const int*)d_in[2];
  const int*   e1l  = (const int*)d_in[3];
  const int*   e2l  = (const int*)d_in[4];
  const float* wemb = (const float*)d_in[5];
  const float* W1   = (const float*)d_in[6];
  const float* b1   = (const float*)d_in[7];
  const float* W2   = (const float*)d_in[8];
  const float* b2   = (const float*)d_in[9];
  float* out = (float*)d_out;

  float* comb  = (float*)d_ws;                        // 256*2354 floats (2.41 MB)
  float* hpart = comb + (size_t)BATCH * CIN;          // 3*256*768 floats (2.36 MB)

  build_combined<<<dim3(6, BATCH), 128, 0, stream>>>(seq, e1p, e2p, e1l, e2l, wemb, comb);
  gemm1<<<dim3(HDIM / BN, BATCH / BM, SPLITK), 256, 0, stream>>>(comb, W1, hpart);
  gemm2<<<BATCH, 64, 0, stream>>>(hpart, b1, W2, b2, out);
}

// Round 2
// 527.730 us; speedup vs baseline: 1.2522x; 1.2522x over previous
//
#include <hip/hip_runtime.h>

#define BATCH 256
#define SEQ   512
#define HDIM  768
#define WDIM  25
#define NLAB  42
#define CIN   2354        // 768*2 + 25*2 + 768
#define CINP  2432        // K padded to 76*32 for BK=32 tiling (pad zeroed)
#define E1W_OFF 1536
#define E2W_OFF 1561
#define CTX_OFF 1586
#define MAXW  10
#define NCHUNK 4          // span split factor (kills the 510-token straggler)

// ---------------------------------------------------------------------------
// K0a: per-(chunk,batch) span partial sums + entity reps.
// grid (4, 256), 192 threads; thread t owns float4 column t (768 = 192*4).
// ---------------------------------------------------------------------------
__global__ __launch_bounds__(192) void span_partial(
    const float* __restrict__ seq,
    const int* __restrict__ e1p, const int* __restrict__ e2p,
    float* __restrict__ comb, float* __restrict__ ctxpart) {
  const int b = blockIdx.y;
  const int cidx = blockIdx.x;           // 0..3
  const int t = threadIdx.x;             // 0..191
  const int e1 = e1p[b];
  const int e2 = e2p[b];
  const float4* row4 = (const float4*)(seq + (size_t)b * SEQ * HDIM);  // 192 f4/token

  if (cidx == 0) {  // entity token reps, fully coalesced float4
    float4* crow4 = (float4*)(comb + (size_t)b * CINP);
    crow4[t]       = row4[e1 * 192 + t];
    crow4[192 + t] = row4[e2 * 192 + t];
  }

  const int s0 = e1 + 1;
  const int n = max(e2 - s0, 0);
  const int clen = (n + NCHUNK - 1) / NCHUNK;
  const int t0 = s0 + cidx * clen;
  const int t1 = min(t0 + clen, e2);

  float4 acc = make_float4(0.f, 0.f, 0.f, 0.f);
  const float4* p = row4 + (size_t)t0 * 192 + t;
  int tok = t0;
  for (; tok + 4 <= t1; tok += 4) {       // 4 tokens in flight
    float4 v0 = p[0], v1 = p[192], v2 = p[384], v3 = p[576];
    acc.x += (v0.x + v1.x) + (v2.x + v3.x);
    acc.y += (v0.y + v1.y) + (v2.y + v3.y);
    acc.z += (v0.z + v1.z) + (v2.z + v3.z);
    acc.w += (v0.w + v1.w) + (v2.w + v3.w);
    p += 768;
  }
  for (; tok < t1; ++tok) {
    float4 v = *p;
    acc.x += v.x; acc.y += v.y; acc.z += v.z; acc.w += v.w;
    p += 192;
  }
  float4* cp = (float4*)ctxpart;
  cp[((size_t)cidx * BATCH + b) * (HDIM / 4) + t] = acc;  // always write (0 if empty)
}

// ---------------------------------------------------------------------------
// K0b: combine 4 partials -> ctx; width embeddings; zero the K-pad.
// grid 256, 192 threads.
// ---------------------------------------------------------------------------
__global__ __launch_bounds__(192) void combine(
    const int* __restrict__ e1p, const int* __restrict__ e2p,
    const int* __restrict__ e1l, const int* __restrict__ e2l,
    const float* __restrict__ wemb,
    const float* __restrict__ ctxpart,
    float* __restrict__ comb) {
  const int b = blockIdx.x;
  const int t = threadIdx.x;
  const int n = max(e2p[b] - e1p[b] - 1, 0);
  const float inv = (n > 0) ? 1.f / (float)n : 0.f;
  float* crow = comb + (size_t)b * CINP;

  const float4* cp = (const float4*)ctxpart;
  const size_t base = (size_t)b * (HDIM / 4) + t;
  const size_t str = (size_t)BATCH * (HDIM / 4);
  float4 a0 = cp[base];
  float4 a1 = cp[base + str];
  float4 a2 = cp[base + 2 * str];
  float4 a3 = cp[base + 3 * str];
  // CTX_OFF (1586) is not 16B-aligned within the row -> scalar stores
  crow[CTX_OFF + 4 * t + 0] = ((a0.x + a1.x) + (a2.x + a3.x)) * inv;
  crow[CTX_OFF + 4 * t + 1] = ((a0.y + a1.y) + (a2.y + a3.y)) * inv;
  crow[CTX_OFF + 4 * t + 2] = ((a0.z + a1.z) + (a2.z + a3.z)) * inv;
  crow[CTX_OFF + 4 * t + 3] = ((a0.w + a1.w) + (a2.w + a3.w)) * inv;

  if (t < WDIM) {
    int w = e1l[b]; w = w < 0 ? 0 : (w > MAXW ? MAXW : w);
    crow[E1W_OFF + t] = wemb[w * WDIM + t];
  } else if (t >= 64 && t < 64 + WDIM) {
    int tt = t - 64;
    int w = e2l[b]; w = w < 0 ? 0 : (w > MAXW ? MAXW : w);
    crow[E2W_OFF + tt] = wemb[w * WDIM + tt];
  }
  if (t < CINP - CIN) crow[CIN + t] = 0.f;   // zero 78-float K pad
}

// ---------------------------------------------------------------------------
// K1: split-K GEMM, double-buffered LDS + register prefetch.
// M=256,N=768,K=2432(pad). BM=32,BN=64,BK=32,SPLITK=4 -> 12*8*4=384 blocks.
// 256 threads, 2m x 4n per thread.
// ---------------------------------------------------------------------------
#define BM 32
#define BN 64
#define BK 32
#define SPLITK 4
#define KCH 608           // CINP / SPLITK, = 19 tiles of BK
#define ASTR 34           // As row stride (even -> b64-friendly a-pair reads)
#define BSTR 68           // Bs row stride (pad breaks 64-stride bank aliasing)

__global__ __launch_bounds__(256) void gemm1(
    const float* __restrict__ comb,
    const float* __restrict__ W1,
    float* __restrict__ hpart) {
  const int nt = blockIdx.x;            // 0..11
  const int mt = blockIdx.y;            // 0..7
  const int ks = blockIdx.z;            // 0..3
  const int tid = threadIdx.x;
  const int k0 = ks * KCH;
  const int m0 = mt * BM;
  const int n0 = nt * BN;

  __shared__ float As[2][BK * ASTR];
  __shared__ float Bs[2][BK * BSTR];

  // A staging: thread -> (m row, 4 consecutive k), stored transposed As[k][m]
  const int am = tid >> 3;              // 0..31
  const int ak = (tid & 7) * 4;         // 0,4,...,28
  // B staging: thread -> (k row bk & bk+16, 4 consecutive n)
  const int bk = tid >> 4;              // 0..15
  const int bn = (tid & 15) * 4;
  // compute mapping: rows 2ty,2ty+1; cols tx*4..tx*4+3
  const int tx = tid & 15;
  const int ty = tid >> 4;

  const float* Aptr = comb + (size_t)(m0 + am) * CINP + k0 + ak;
  const float* Bptr = W1 + (size_t)(k0 + bk) * HDIM + n0 + bn;

  const float4 z4 = make_float4(0.f, 0.f, 0.f, 0.f);
  float4 ar, br0, br1;

  // prologue: fetch tile 0
  ar = *(const float4*)Aptr;
  br0 = (k0 + bk < CIN) ? *(const float4*)Bptr : z4;
  br1 = (k0 + bk + 16 < CIN) ? *(const float4*)(Bptr + 16 * HDIM) : z4;
  As[0][(ak + 0) * ASTR + am] = ar.x;
  As[0][(ak + 1) * ASTR + am] = ar.y;
  As[0][(ak + 2) * ASTR + am] = ar.z;
  As[0][(ak + 3) * ASTR + am] = ar.w;
  *(float4*)&Bs[0][bk * BSTR + bn] = br0;
  *(float4*)&Bs[0][(bk + 16) * BSTR + bn] = br1;
  __syncthreads();

  float acc[2][4] = {{0.f,0.f,0.f,0.f},{0.f,0.f,0.f,0.f}};
  const int NT = KCH / BK;              // 19
  int cur = 0;
  for (int t = 0; t < NT; ++t) {
    if (t + 1 < NT) {                   // issue next tile's global loads now
      const float* Ap = Aptr + (t + 1) * BK;
      const float* Bp = Bptr + (size_t)(t + 1) * BK * HDIM;
      int kg = k0 + (t + 1) * BK + bk;
      ar = *(const float4*)Ap;
      br0 = (kg < CIN) ? *(const float4*)Bp : z4;
      br1 = (kg + 16 < CIN) ? *(const float4*)(Bp + 16 * HDIM) : z4;
    }
    const float* Asc = As[cur];
    const float* Bsc = Bs[cur];
#pragma unroll
    for (int k = 0; k < BK; ++k) {
      float a0 = Asc[k * ASTR + 2 * ty];
      float a1 = Asc[k * ASTR + 2 * ty + 1];
      float4 bv = *(const float4*)&Bsc[k * BSTR + tx * 4];
      acc[0][0] += a0 * bv.x; acc[0][1] += a0 * bv.y;
      acc[0][2] += a0 * bv.z; acc[0][3] += a0 * bv.w;
      acc[1][0] += a1 * bv.x; acc[1][1] += a1 * bv.y;
      acc[1][2] += a1 * bv.z; acc[1][3] += a1 * bv.w;
    }
    if (t + 1 < NT) {
      __syncthreads();
      int nxt = cur ^ 1;
      As[nxt][(ak + 0) * ASTR + am] = ar.x;
      As[nxt][(ak + 1) * ASTR + am] = ar.y;
      As[nxt][(ak + 2) * ASTR + am] = ar.z;
      As[nxt][(ak + 3) * ASTR + am] = ar.w;
      *(float4*)&Bs[nxt][bk * BSTR + bn] = br0;
      *(float4*)&Bs[nxt][(bk + 16) * BSTR + bn] = br1;
      __syncthreads();
      cur = nxt;
    }
  }

  float* outp = hpart + (size_t)ks * BATCH * HDIM;
#pragma unroll
  for (int i = 0; i < 2; ++i) {
    int m = m0 + 2 * ty + i;
    float4 v = make_float4(acc[i][0], acc[i][1], acc[i][2], acc[i][3]);
    *(float4*)&outp[(size_t)m * HDIM + n0 + tx * 4] = v;
  }
}

// ---------------------------------------------------------------------------
// K2: sum SPLITK partials + b1 + ReLU, then [768] x W2[768,42] + b2.
// 256 threads: 6 k-groups x 42 cols (252 active) + LDS reduce.
// ---------------------------------------------------------------------------
__global__ __launch_bounds__(256) void gemm2(
    const float* __restrict__ hpart,
    const float* __restrict__ b1,
    const float* __restrict__ W2,
    const float* __restrict__ b2,
    float* __restrict__ out) {
  const int m = blockIdx.x;
  const int tid = threadIdx.x;
  __shared__ float hs[HDIM];
  __shared__ float part[6 * NLAB];

  const float* p = hpart + (size_t)m * HDIM;
  const size_t str = (size_t)BATCH * HDIM;
  for (int i = tid; i < HDIM; i += 256) {
    float v = (p[i] + p[i + str]) + (p[i + 2 * str] + p[i + 3 * str]) + b1[i];
    hs[i] = v > 0.f ? v : 0.f;
  }
  __syncthreads();

  if (tid < 252) {
    const int g = tid / NLAB;           // 0..5
    const int c = tid - g * NLAB;       // 0..41
    const int kk0 = g * 128;
    float a = 0.f;
#pragma unroll 8
    for (int j = 0; j < 128; ++j) {
      int k = kk0 + j;
      a += hs[k] * W2[k * NLAB + c];
    }
    part[g * NLAB + c] = a;
  }
  __syncthreads();

  if (tid < NLAB) {
    float r = b2[tid];
#pragma unroll
    for (int g = 0; g < 6; ++g) r += part[g * NLAB + tid];
    out[m * NLAB + tid] = r;
  }
}

// ---------------------------------------------------------------------------
extern "C" void kernel_launch(void* const* d_in, const int* in_sizes, int n_in,
                              void* d_out, int out_size, void* d_ws, size_t ws_size,
                              hipStream_t stream) {
  const float* seq  = (const float*)d_in[0];
  const int*   e1p  = (const int*)d_in[1];
  const int*   e2p  = (const int*)d_in[2];
  const int*   e1l  = (const int*)d_in[3];
  const int*   e2l  = (const int*)d_in[4];
  const float* wemb = (const float*)d_in[5];
  const float* W1   = (const float*)d_in[6];
  const float* b1   = (const float*)d_in[7];
  const float* W2   = (const float*)d_in[8];
  const float* b2   = (const float*)d_in[9];
  float* out = (float*)d_out;

  float* comb    = (float*)d_ws;                                  // 256*2432 f
  float* ctxpart = comb + (size_t)BATCH * CINP;                   // 4*256*768 f
  float* hpart   = ctxpart + (size_t)NCHUNK * BATCH * HDIM;       // 4*256*768 f

  span_partial<<<dim3(NCHUNK, BATCH), 192, 0, stream>>>(seq, e1p, e2p, comb, ctxpart);
  combine<<<BATCH, 192, 0, stream>>>(e1p, e2p, e1l, e2l, wemb, ctxpart, comb);
  gemm1<<<dim3(HDIM / BN, BATCH / BM, SPLITK), 256, 0, stream>>>(comb, W1, hpart);
  gemm2<<<BATCH, 256, 0, stream>>>(hpart, b1, W2, b2, out);
}